// Round 2
// baseline (124.607 us; speedup 1.0000x reference)
//
#include <hip/hip_runtime.h>
#include <hip/hip_bf16.h>
#include <stdint.h>

typedef short bf16x8 __attribute__((ext_vector_type(8)));
typedef float f32x4 __attribute__((ext_vector_type(4)));

#define NN 4096

static __device__ __forceinline__ short f2b(float f) {
    union { float f; uint32_t u; } a; a.f = f;
    uint32_t r = a.u + 0x7FFFu + ((a.u >> 16) & 1u);
    return (short)(r >> 16);
}

// ---- output region offsets (in floats) ----
#define OFF_QMV   0UL
#define OFF_KMV   8388608UL
#define OFF_VMV   16777216UL
#define OFF_VMVQ  25165824UL
#define OFF_QS    33554432UL
#define OFF_KS    35651584UL
#define OFF_VS    37748736UL
#define OFF_VSQ   39845888UL

// ---- ws layout (bf16 elements) ----
// Bmv:   [task][y:9][ct:8][lane:64][e:8]   2*9*8*512  = 73728
// Bs2mv: [task][kk:4][ct:8][lane:64][e:8]  2*4*8*512  = 32768
#define WS_BMV_END   73728
#define WS_TOTAL     106496

__global__ __launch_bounds__(256) void prep_pack(
    const float* __restrict__ qwmv,   const float* __restrict__ qws2mv,
    const float* __restrict__ kvwmv,  const float* __restrict__ kvws2mv,
    short* __restrict__ ws)
{
    int id = blockIdx.x * 256 + threadIdx.x;
    if (id >= WS_TOTAL) return;
    float v;
    if (id < WS_BMV_END) {
        int rem = id; int task = rem / 36864; rem -= task * 36864;
        int y = rem / 4096; rem -= y * 4096;
        int ct = rem >> 9; int l = (rem >> 3) & 63; int e = rem & 7;
        int o = ct * 16 + (l & 15);
        int i = (l >> 4) * 8 + e;
        const float* w = (task == 0 || o >= 64) ? kvwmv : qwmv;
        v = w[(o * 32 + i) * 9 + y];
    } else {
        int rem = id - WS_BMV_END; int task = rem / 16384; rem -= task * 16384;
        int kk = rem / 4096; rem -= kk * 4096;
        int ct = rem >> 9; int l = (rem >> 3) & 63; int e = rem & 7;
        int o = ct * 16 + (l & 15);
        int k = kk * 32 + (l >> 4) * 8 + e;
        const float* w = (task == 0 || o >= 64) ? kvws2mv : qws2mv;
        v = w[o * 128 + k];
    }
    ws[id] = f2b(v);
}

// ======================= MV outputs (validated path) ========================
__global__ __launch_bounds__(256) void fused_mv(
    const float* __restrict__ inputs, const float* __restrict__ scalars,
    const int* __restrict__ q_idx,    const int* __restrict__ kv_idx,
    const short* __restrict__ ws,     float* __restrict__ out)
{
    const int GR[16]   = {0,1,1,1,1,2,2,2,2,2,2,3,3,3,3,4};
    const int SRC[16]  = {-1,0,-1,-1,-1,2,3,4,-1,-1,-1,8,9,10,-1,14};
    const int EMAP[16] = {0,5,0,0,0,6,6,6,0,0,0,7,7,7,0,8};

    __shared__ short XA[16 * 16 * 32];  // [x][r][i] bf16
    __shared__ short XS[16 * 136];      // [r][k] pad 136

    const int tid  = threadIdx.x;
    const int bid  = blockIdx.x;
    const int tile = bid & 255;
    const int b    = (bid >> 8) & 1;
    const int task = bid >> 9;          // 0 = kv-task, 1 = q-task
    const int n0   = tile * 16;
    const int* ridx = task ? q_idx : kv_idx;

    for (int t = tid; t < 2048; t += 256) {      // mv: 16 rows * 128 float4
        int r = t >> 7, c4 = t & 127;
        int m = ridx[n0 + r];
        const float4 v = *(const float4*)(inputs + ((size_t)(b * NN + m)) * 512 + c4 * 4);
        int i = c4 >> 2, x0 = (c4 & 3) * 4;
        XA[((x0 + 0) * 16 + r) * 32 + i] = f2b(v.x);
        XA[((x0 + 1) * 16 + r) * 32 + i] = f2b(v.y);
        XA[((x0 + 2) * 16 + r) * 32 + i] = f2b(v.z);
        XA[((x0 + 3) * 16 + r) * 32 + i] = f2b(v.w);
    }
    for (int t = tid; t < 512; t += 256) {       // scalars: 16 rows * 32 float4
        int r = t >> 5, c4 = t & 31;
        int m = ridx[n0 + r];
        const float4 v = *(const float4*)(scalars + ((size_t)(b * NN + m)) * 128 + c4 * 4);
        XS[r * 136 + c4 * 4 + 0] = f2b(v.x);
        XS[r * 136 + c4 * 4 + 1] = f2b(v.y);
        XS[r * 136 + c4 * 4 + 2] = f2b(v.z);
        XS[r * 136 + c4 * 4 + 3] = f2b(v.w);
    }
    __syncthreads();

    const int w  = tid >> 6;
    const int l  = tid & 63;
    const int lr = l & 15;
    const int lg = l >> 4;

    #pragma unroll
    for (int cc = 0; cc < 2; ++cc) {
        const int ct = 2 * w + cc;
        bf16x8 Bg[9];
        #pragma unroll
        for (int y = 0; y < 9; ++y)
            Bg[y] = *(const bf16x8*)(ws + ((((size_t)task * 9 + y) * 8 + ct) * 64 + l) * 8);

        const int o    = ct * 16 + lr;
        const int hid  = (o >> 3) & 7, head = o & 7;
        size_t obase = task ? ((o >= 64) ? OFF_VMVQ : OFF_QMV)
                            : ((o >= 64) ? OFF_VMV  : OFF_KMV);
        const size_t rowco = obase + (((size_t)b * 8 + head) * NN) * 128 + (size_t)hid * 16;

        #pragma unroll
        for (int xc = 0; xc < 4; ++xc) {
            f32x4 acc[4];
            #pragma unroll
            for (int q = 0; q < 4; ++q) {
                const int x = xc * 4 + q;
                f32x4 a0 = {0.f, 0.f, 0.f, 0.f};
                bf16x8 am = *(const bf16x8*)(XA + (x * 16 + lr) * 32 + lg * 8);
                a0 = __builtin_amdgcn_mfma_f32_16x16x32_bf16(am, Bg[GR[x]], a0, 0, 0, 0);
                if (SRC[x] >= 0) {
                    bf16x8 as = *(const bf16x8*)(XA + (SRC[x] * 16 + lr) * 32 + lg * 8);
                    a0 = __builtin_amdgcn_mfma_f32_16x16x32_bf16(as, Bg[EMAP[x]], a0, 0, 0, 0);
                }
                if (x == 0) {
                    #pragma unroll
                    for (int kk = 0; kk < 4; ++kk) {
                        bf16x8 bs2 = *(const bf16x8*)(ws + WS_BMV_END +
                                       ((((size_t)task * 4 + kk) * 8 + ct) * 64 + l) * 8);
                        bf16x8 axs = *(const bf16x8*)(XS + lr * 136 + kk * 32 + lg * 8);
                        a0 = __builtin_amdgcn_mfma_f32_16x16x32_bf16(axs, bs2, a0, 0, 0, 0);
                    }
                }
                acc[q] = a0;
            }
            #pragma unroll
            for (int j = 0; j < 4; ++j) {
                const int n = n0 + lg * 4 + j;
                float4 vv = make_float4(acc[0][j], acc[1][j], acc[2][j], acc[3][j]);
                *(float4*)(out + rowco + (size_t)n * 128 + xc * 4) = vv;
            }
        }
    }
}

// ===================== S outputs (standalone, no LDS/ws) ====================
__global__ __launch_bounds__(256) void s_proj(
    const float* __restrict__ inputs, const float* __restrict__ scalars,
    const float* __restrict__ q_b_s,  const float* __restrict__ kv_b_s,
    const float* __restrict__ qwmv2s, const float* __restrict__ qws2s,
    const float* __restrict__ kvwmv2s,const float* __restrict__ kvws2s,
    const int* __restrict__ q_idx,    const int* __restrict__ kv_idx,
    float* __restrict__ out)
{
    const int tid  = threadIdx.x;
    const int bid  = blockIdx.x;
    const int tile = bid & 255;
    const int b    = (bid >> 8) & 1;
    const int task = bid >> 9;
    const int n0   = tile * 16;
    const int* ridx = task ? q_idx : kv_idx;

    const int w  = tid >> 6;
    const int l  = tid & 63;
    const int lr = l & 15;
    const int lg = l >> 4;

    // This lane supplies A-row lr: gathered source row m.
    const int m = ridx[n0 + lr];

    // A fragment, mv blade-0: A[lr][k=lg*8+e] = inputs[b][m][lg*8+e][0]
    const float* mvrow = inputs + ((size_t)(b * NN + m)) * 512;
    bf16x8 a0;
    #pragma unroll
    for (int e = 0; e < 8; ++e) a0[e] = f2b(mvrow[(lg * 8 + e) * 16]);

    // A fragments, scalars: as[c][e] = scalars[b][m][c*32 + lg*8 + e]
    const float* srow = scalars + ((size_t)(b * NN + m)) * 128;
    bf16x8 as[4];
    #pragma unroll
    for (int c = 0; c < 4; ++c) {
        float4 v0 = *(const float4*)(srow + c * 32 + lg * 8);
        float4 v1 = *(const float4*)(srow + c * 32 + lg * 8 + 4);
        as[c][0] = f2b(v0.x); as[c][1] = f2b(v0.y);
        as[c][2] = f2b(v0.z); as[c][3] = f2b(v0.w);
        as[c][4] = f2b(v1.x); as[c][5] = f2b(v1.y);
        as[c][6] = f2b(v1.z); as[c][7] = f2b(v1.w);
    }

    #pragma unroll
    for (int j8 = 0; j8 < 8; ++j8) {
        const int ct = w * 8 + j8;
        const int o  = ct * 16 + lr;                  // B-col channel for this lane
        const int usekv = (task == 0 || o >= 256);
        const float* wmv2s = usekv ? kvwmv2s : qwmv2s;
        const float* ws2s  = usekv ? kvws2s  : qws2s;

        f32x4 acc = {0.f, 0.f, 0.f, 0.f};
        // kt=0: mv2s — B[k=lg*8+e][col] = wmv2s[o][lg*8+e]
        {
            const float* p = wmv2s + (size_t)o * 32 + lg * 8;
            float4 u0 = *(const float4*)p, u1 = *(const float4*)(p + 4);
            bf16x8 bf;
            bf[0] = f2b(u0.x); bf[1] = f2b(u0.y); bf[2] = f2b(u0.z); bf[3] = f2b(u0.w);
            bf[4] = f2b(u1.x); bf[5] = f2b(u1.y); bf[6] = f2b(u1.z); bf[7] = f2b(u1.w);
            acc = __builtin_amdgcn_mfma_f32_16x16x32_bf16(a0, bf, acc, 0, 0, 0);
        }
        // kt=1..4: s2s chunks
        #pragma unroll
        for (int c = 0; c < 4; ++c) {
            const float* p = ws2s + (size_t)o * 128 + c * 32 + lg * 8;
            float4 u0 = *(const float4*)p, u1 = *(const float4*)(p + 4);
            bf16x8 bf;
            bf[0] = f2b(u0.x); bf[1] = f2b(u0.y); bf[2] = f2b(u0.z); bf[3] = f2b(u0.w);
            bf[4] = f2b(u1.x); bf[5] = f2b(u1.y); bf[6] = f2b(u1.z); bf[7] = f2b(u1.w);
            acc = __builtin_amdgcn_mfma_f32_16x16x32_bf16(as[c], bf, acc, 0, 0, 0);
        }

        float bias; size_t obase;
        if (task == 0)    { obase = (o >= 256) ? OFF_VS : OFF_KS; bias = kv_b_s[o]; }
        else if (o < 256) { obase = OFF_QS;  bias = q_b_s[o]; }
        else              { obase = OFF_VSQ; bias = kv_b_s[o]; }
        const int hid = (o >> 3) & 31, head = o & 7;
        const size_t co = obase + (((size_t)b * 8 + head) * NN) * 32 + hid;
        #pragma unroll
        for (int j = 0; j < 4; ++j) {
            const int n = n0 + lg * 4 + j;
            out[co + (size_t)n * 32] = acc[j] + bias;
        }
    }
}

extern "C" void kernel_launch(void* const* d_in, const int* in_sizes, int n_in,
                              void* d_out, int out_size, void* d_ws, size_t ws_size,
                              hipStream_t stream) {
    const float* inputs  = (const float*)d_in[0];
    const float* scalars = (const float*)d_in[1];
    const float* qwmv    = (const float*)d_in[2];
    const float* qws2mv  = (const float*)d_in[3];
    const float* qwmv2s  = (const float*)d_in[4];
    const float* qws2s   = (const float*)d_in[5];
    const float* qbs     = (const float*)d_in[6];
    const float* kvwmv   = (const float*)d_in[7];
    const float* kvws2mv = (const float*)d_in[8];
    const float* kvwmv2s = (const float*)d_in[9];
    const float* kvws2s  = (const float*)d_in[10];
    const float* kvbs    = (const float*)d_in[11];
    const int*   qidx    = (const int*)d_in[12];
    const int*   kvidx   = (const int*)d_in[13];
    short* ws   = (short*)d_ws;            // 212,992 B of scratch used
    float* outp = (float*)d_out;

    prep_pack<<<WS_TOTAL / 256, 256, 0, stream>>>(
        qwmv, qws2mv, kvwmv, kvws2mv, ws);

    fused_mv<<<1024, 256, 0, stream>>>(
        inputs, scalars, qidx, kvidx, ws, outp);

    s_proj<<<1024, 256, 0, stream>>>(
        inputs, scalars, qbs, kvbs, qwmv2s, qws2s, kvwmv2s, kvws2s,
        qidx, kvidx, outp);
}

// Round 3
// 91.851 us; speedup vs baseline: 1.3566x; 1.3566x over previous
//
#include <hip/hip_runtime.h>
#include <hip/hip_bf16.h>
#include <stdint.h>

typedef short bf16x8 __attribute__((ext_vector_type(8)));
typedef float f32x4 __attribute__((ext_vector_type(4)));

#define NN 4096

static __device__ __forceinline__ short f2b(float f) {
    union { float f; uint32_t u; } a; a.f = f;
    uint32_t r = a.u + 0x7FFFu + ((a.u >> 16) & 1u);
    return (short)(r >> 16);
}

// ---- output region offsets (in floats) ----
#define OFF_QMV   0UL
#define OFF_KMV   8388608UL
#define OFF_VMV   16777216UL
#define OFF_VMVQ  25165824UL
#define OFF_QS    33554432UL
#define OFF_KS    35651584UL
#define OFF_VS    37748736UL
#define OFF_VSQ   39845888UL

// ---- ws layout (bf16 elements) ----
// Bmv:   [task][y:9][ct:8][lane:64][e:8]    2*9*8*512   = 73728
// Bs2mv: [task][kk:4][ct:8][lane:64][e:8]   2*4*8*512   = 32768
// SW:    [task][ct:32][lr:16][k:160]        2*32*16*160 = 163840  (plain rows)
// A0:    [b:2][n:4096][i:32]                2*4096*32   = 262144  (input blade-0)
#define WS_BMV_END   73728
#define WS_SW_BASE   106496
#define WS_A0_BASE   270336
#define WS_TOTAL     532480

// col-channel mapping for the S GEMM: o(ct,lr) — bijective, bit-disjoint
static __device__ __forceinline__ int s_chan(int ct, int lr) {
    int hid = (ct & 3) + 4 * (lr >> 3) + 8 * (ct >> 2);
    return (lr & 7) + 8 * hid;
}

__global__ __launch_bounds__(256) void prep_pack(
    const float* __restrict__ inputs,
    const float* __restrict__ qwmv,   const float* __restrict__ qws2mv,
    const float* __restrict__ qwmv2s, const float* __restrict__ qws2s,
    const float* __restrict__ kvwmv,  const float* __restrict__ kvws2mv,
    const float* __restrict__ kvwmv2s,const float* __restrict__ kvws2s,
    short* __restrict__ ws)
{
    int id = blockIdx.x * 256 + threadIdx.x;
    if (id >= WS_TOTAL) return;
    float v;
    if (id < WS_BMV_END) {
        int rem = id; int task = rem / 36864; rem -= task * 36864;
        int y = rem / 4096; rem -= y * 4096;
        int ct = rem >> 9; int l = (rem >> 3) & 63; int e = rem & 7;
        int o = ct * 16 + (l & 15);
        int i = (l >> 4) * 8 + e;
        const float* w = (task == 0 || o >= 64) ? kvwmv : qwmv;
        v = w[(o * 32 + i) * 9 + y];
    } else if (id < WS_SW_BASE) {
        int rem = id - WS_BMV_END; int task = rem / 16384; rem -= task * 16384;
        int kk = rem / 4096; rem -= kk * 4096;
        int ct = rem >> 9; int l = (rem >> 3) & 63; int e = rem & 7;
        int o = ct * 16 + (l & 15);
        int k = kk * 32 + (l >> 4) * 8 + e;
        const float* w = (task == 0 || o >= 64) ? kvws2mv : qws2mv;
        v = w[o * 128 + k];
    } else if (id < WS_A0_BASE) {
        int rem = id - WS_SW_BASE; int task = rem / 81920; rem -= task * 81920;
        int ct = rem / 2560; rem -= ct * 2560;
        int lr = rem / 160;  int k = rem - lr * 160;
        int o = s_chan(ct, lr);
        if (k < 32) {
            const float* w = (task == 0 || o >= 256) ? kvwmv2s : qwmv2s;
            v = w[o * 32 + k];
        } else {
            const float* w = (task == 0 || o >= 256) ? kvws2s : qws2s;
            v = w[o * 128 + (k - 32)];
        }
    } else {
        int rem = id - WS_A0_BASE;          // (b*4096 + n)*32 + i
        v = inputs[(size_t)rem * 16];       // blade 0 of channel i, row (b,n)
    }
    ws[id] = f2b(v);
}

// ======================= MV outputs (validated path; XA padded) =============
__global__ __launch_bounds__(256) void fused_mv(
    const float* __restrict__ inputs, const float* __restrict__ scalars,
    const int* __restrict__ q_idx,    const int* __restrict__ kv_idx,
    const short* __restrict__ ws,     float* __restrict__ out)
{
    const int GR[16]   = {0,1,1,1,1,2,2,2,2,2,2,3,3,3,3,4};
    const int SRC[16]  = {-1,0,-1,-1,-1,2,3,4,-1,-1,-1,8,9,10,-1,14};
    const int EMAP[16] = {0,5,0,0,0,6,6,6,0,0,0,7,7,7,0,8};

    __shared__ short XA[16 * 16 * 40];  // [x][r][i] bf16, row stride 40 (80 B: bank-spread)
    __shared__ short XS[16 * 136];      // [r][k] pad 136

    const int tid  = threadIdx.x;
    const int bid  = blockIdx.x;
    const int tile = bid & 255;
    const int b    = (bid >> 8) & 1;
    const int task = bid >> 9;          // 0 = kv-task, 1 = q-task
    const int n0   = tile * 16;
    const int* ridx = task ? q_idx : kv_idx;

    for (int t = tid; t < 2048; t += 256) {      // mv: 16 rows * 128 float4
        int r = t >> 7, c4 = t & 127;
        int m = ridx[n0 + r];
        const float4 v = *(const float4*)(inputs + ((size_t)(b * NN + m)) * 512 + c4 * 4);
        int i = c4 >> 2, x0 = (c4 & 3) * 4;
        XA[((x0 + 0) * 16 + r) * 40 + i] = f2b(v.x);
        XA[((x0 + 1) * 16 + r) * 40 + i] = f2b(v.y);
        XA[((x0 + 2) * 16 + r) * 40 + i] = f2b(v.z);
        XA[((x0 + 3) * 16 + r) * 40 + i] = f2b(v.w);
    }
    for (int t = tid; t < 512; t += 256) {       // scalars: 16 rows * 32 float4
        int r = t >> 5, c4 = t & 31;
        int m = ridx[n0 + r];
        const float4 v = *(const float4*)(scalars + ((size_t)(b * NN + m)) * 128 + c4 * 4);
        XS[r * 136 + c4 * 4 + 0] = f2b(v.x);
        XS[r * 136 + c4 * 4 + 1] = f2b(v.y);
        XS[r * 136 + c4 * 4 + 2] = f2b(v.z);
        XS[r * 136 + c4 * 4 + 3] = f2b(v.w);
    }
    __syncthreads();

    const int w  = tid >> 6;
    const int l  = tid & 63;
    const int lr = l & 15;
    const int lg = l >> 4;

    #pragma unroll
    for (int cc = 0; cc < 2; ++cc) {
        const int ct = 2 * w + cc;
        bf16x8 Bg[9];
        #pragma unroll
        for (int y = 0; y < 9; ++y)
            Bg[y] = *(const bf16x8*)(ws + ((((size_t)task * 9 + y) * 8 + ct) * 64 + l) * 8);

        const int o    = ct * 16 + lr;
        const int hid  = (o >> 3) & 7, head = o & 7;
        size_t obase = task ? ((o >= 64) ? OFF_VMVQ : OFF_QMV)
                            : ((o >= 64) ? OFF_VMV  : OFF_KMV);
        const size_t rowco = obase + (((size_t)b * 8 + head) * NN) * 128 + (size_t)hid * 16;

        #pragma unroll
        for (int xc = 0; xc < 4; ++xc) {
            f32x4 acc[4];
            #pragma unroll
            for (int q = 0; q < 4; ++q) {
                const int x = xc * 4 + q;
                f32x4 a0 = {0.f, 0.f, 0.f, 0.f};
                bf16x8 am = *(const bf16x8*)(XA + (x * 16 + lr) * 40 + lg * 8);
                a0 = __builtin_amdgcn_mfma_f32_16x16x32_bf16(am, Bg[GR[x]], a0, 0, 0, 0);
                if (SRC[x] >= 0) {
                    bf16x8 as = *(const bf16x8*)(XA + (SRC[x] * 16 + lr) * 40 + lg * 8);
                    a0 = __builtin_amdgcn_mfma_f32_16x16x32_bf16(as, Bg[EMAP[x]], a0, 0, 0, 0);
                }
                if (x == 0) {
                    #pragma unroll
                    for (int kk = 0; kk < 4; ++kk) {
                        bf16x8 bs2 = *(const bf16x8*)(ws + WS_BMV_END +
                                       ((((size_t)task * 4 + kk) * 8 + ct) * 64 + l) * 8);
                        bf16x8 axs = *(const bf16x8*)(XS + lr * 136 + kk * 32 + lg * 8);
                        a0 = __builtin_amdgcn_mfma_f32_16x16x32_bf16(axs, bs2, a0, 0, 0, 0);
                    }
                }
                acc[q] = a0;
            }
            #pragma unroll
            for (int j = 0; j < 4; ++j) {
                const int n = n0 + lg * 4 + j;
                float4 vv = make_float4(acc[0][j], acc[1][j], acc[2][j], acc[3][j]);
                *(float4*)(out + rowco + (size_t)n * 128 + xc * 4) = vv;
            }
        }
    }
}

// ============= S outputs: bf16 packed weights, float4 stores ================
__global__ __launch_bounds__(256) void s_proj(
    const float* __restrict__ scalars,
    const float* __restrict__ q_b_s,  const float* __restrict__ kv_b_s,
    const int* __restrict__ q_idx,    const int* __restrict__ kv_idx,
    const short* __restrict__ ws,     float* __restrict__ out)
{
    const int tid  = threadIdx.x;
    const int bid  = blockIdx.x;
    const int tile = bid & 255;
    const int b    = (bid >> 8) & 1;
    const int task = bid >> 9;
    const int n0   = tile * 16;
    const int* ridx = task ? q_idx : kv_idx;

    const int w  = tid >> 6;
    const int l  = tid & 63;
    const int lr = l & 15;
    const int lg = l >> 4;

    const int m = ridx[n0 + lr];   // this lane supplies A-row lr

    // A fragment, mv blade-0 (bf16 table in ws)
    bf16x8 a0 = *(const bf16x8*)(ws + WS_A0_BASE + ((size_t)(b * NN + m)) * 32 + lg * 8);

    // A fragments, scalars
    const float* srow = scalars + ((size_t)(b * NN + m)) * 128;
    bf16x8 as[4];
    #pragma unroll
    for (int c = 0; c < 4; ++c) {
        float4 v0 = *(const float4*)(srow + c * 32 + lg * 8);
        float4 v1 = *(const float4*)(srow + c * 32 + lg * 8 + 4);
        as[c][0] = f2b(v0.x); as[c][1] = f2b(v0.y);
        as[c][2] = f2b(v0.z); as[c][3] = f2b(v0.w);
        as[c][4] = f2b(v1.x); as[c][5] = f2b(v1.y);
        as[c][6] = f2b(v1.z); as[c][7] = f2b(v1.w);
    }

    #pragma unroll
    for (int q8 = 0; q8 < 2; ++q8) {            // two quads of ct
        f32x4 acc4[4];
        #pragma unroll
        for (int jj = 0; jj < 4; ++jj) {
            const int ct = w * 8 + q8 * 4 + jj;
            const short* bp = ws + WS_SW_BASE +
                              (((size_t)task * 32 + ct) * 16 + lr) * 160 + lg * 8;
            f32x4 acc = {0.f, 0.f, 0.f, 0.f};
            acc = __builtin_amdgcn_mfma_f32_16x16x32_bf16(a0, *(const bf16x8*)bp, acc, 0, 0, 0);
            #pragma unroll
            for (int c = 0; c < 4; ++c)
                acc = __builtin_amdgcn_mfma_f32_16x16x32_bf16(
                          as[c], *(const bf16x8*)(bp + 32 + c * 32), acc, 0, 0, 0);
            acc4[jj] = acc;
        }
        const int hidbase = 16 * w + 8 * q8 + 4 * (lr >> 3);
        const int head = lr & 7;
        float bs[4];
        #pragma unroll
        for (int jj = 0; jj < 4; ++jj) {
            const int o = head + 8 * (hidbase + jj);
            bs[jj] = (task == 0) ? kv_b_s[o] : ((o < 256) ? q_b_s[o] : kv_b_s[o]);
        }
        size_t obase = task ? ((hidbase < 32) ? OFF_QS : OFF_VSQ)
                            : ((hidbase < 32) ? OFF_KS : OFF_VS);
        const size_t co = obase + (((size_t)b * 8 + head) * NN) * 32 + (hidbase & 31);
        #pragma unroll
        for (int j = 0; j < 4; ++j) {
            const int n = n0 + lg * 4 + j;
            float4 vv = make_float4(acc4[0][j] + bs[0], acc4[1][j] + bs[1],
                                    acc4[2][j] + bs[2], acc4[3][j] + bs[3]);
            *(float4*)(out + co + (size_t)n * 32) = vv;
        }
    }
}

extern "C" void kernel_launch(void* const* d_in, const int* in_sizes, int n_in,
                              void* d_out, int out_size, void* d_ws, size_t ws_size,
                              hipStream_t stream) {
    const float* inputs  = (const float*)d_in[0];
    const float* scalars = (const float*)d_in[1];
    const float* qwmv    = (const float*)d_in[2];
    const float* qws2mv  = (const float*)d_in[3];
    const float* qwmv2s  = (const float*)d_in[4];
    const float* qws2s   = (const float*)d_in[5];
    const float* qbs     = (const float*)d_in[6];
    const float* kvwmv   = (const float*)d_in[7];
    const float* kvws2mv = (const float*)d_in[8];
    const float* kvwmv2s = (const float*)d_in[9];
    const float* kvws2s  = (const float*)d_in[10];
    const float* kvbs    = (const float*)d_in[11];
    const int*   qidx    = (const int*)d_in[12];
    const int*   kvidx   = (const int*)d_in[13];
    short* ws   = (short*)d_ws;            // 1,064,960 B of scratch used
    float* outp = (float*)d_out;

    prep_pack<<<WS_TOTAL / 256, 256, 0, stream>>>(
        inputs, qwmv, qws2mv, qwmv2s, qws2s, kvwmv, kvws2mv, kvwmv2s, kvws2s, ws);

    fused_mv<<<1024, 256, 0, stream>>>(
        inputs, scalars, qidx, kvidx, ws, outp);

    s_proj<<<1024, 256, 0, stream>>>(
        scalars, qbs, kvbs, qidx, kvidx, ws, outp);
}

// Round 4
// 88.419 us; speedup vs baseline: 1.4093x; 1.0388x over previous
//
#include <hip/hip_runtime.h>
#include <hip/hip_bf16.h>
#include <stdint.h>

typedef short bf16x8 __attribute__((ext_vector_type(8)));
typedef float f32x4 __attribute__((ext_vector_type(4)));

#define NN 4096

static __device__ __forceinline__ short f2b(float f) {
    union { float f; uint32_t u; } a; a.f = f;
    uint32_t r = a.u + 0x7FFFu + ((a.u >> 16) & 1u);
    return (short)(r >> 16);
}

// ---- output region offsets (in floats) ----
#define OFF_QMV   0UL
#define OFF_KMV   8388608UL
#define OFF_VMV   16777216UL
#define OFF_VMVQ  25165824UL
#define OFF_QS    33554432UL
#define OFF_KS    35651584UL
#define OFF_VS    37748736UL
#define OFF_VSQ   39845888UL

// ---- ws layout (bf16 elements) ----
// Bmv:   [task][y:9][ct:8][lane:64][e:8]    = 73728
// Bs2mv: [task][kk:4][ct:8][lane:64][e:8]   = 32768
// SW:    [task][ct:32][lr:16][k:160]        = 163840
// TS:    [b:2][n:4096][k:128]   bf16 scalars copy      = 1048576
// TIN:   [b:2][n:4096][x:16][i:32] bf16 transposed mv  = 4194304
#define WS_BMV_END   73728
#define WS_SW_BASE   106496
#define WS_TS_BASE   270336
#define WS_PACK_END  1318912
#define WS_TIN_BASE  1318912
#define WS_TOTAL     5513216   // shorts -> 11,026,432 bytes of scratch

// col-channel mapping for the S GEMM: o(ct,lr) — bijective, bit-disjoint
static __device__ __forceinline__ int s_chan(int ct, int lr) {
    int hid = (ct & 3) + 4 * (lr >> 3) + 8 * (ct >> 2);
    return (lr & 7) + 8 * hid;
}

__global__ __launch_bounds__(256) void prep_pack(
    const float* __restrict__ scalars,
    const float* __restrict__ qwmv,   const float* __restrict__ qws2mv,
    const float* __restrict__ qwmv2s, const float* __restrict__ qws2s,
    const float* __restrict__ kvwmv,  const float* __restrict__ kvws2mv,
    const float* __restrict__ kvwmv2s,const float* __restrict__ kvws2s,
    short* __restrict__ ws)
{
    int id = blockIdx.x * 256 + threadIdx.x;
    if (id >= WS_PACK_END) return;
    float v;
    if (id < WS_BMV_END) {
        int rem = id; int task = rem / 36864; rem -= task * 36864;
        int y = rem / 4096; rem -= y * 4096;
        int ct = rem >> 9; int l = (rem >> 3) & 63; int e = rem & 7;
        int o = ct * 16 + (l & 15);
        int i = (l >> 4) * 8 + e;
        const float* w = (task == 0 || o >= 64) ? kvwmv : qwmv;
        v = w[(o * 32 + i) * 9 + y];
    } else if (id < WS_SW_BASE) {
        int rem = id - WS_BMV_END; int task = rem / 16384; rem -= task * 16384;
        int kk = rem / 4096; rem -= kk * 4096;
        int ct = rem >> 9; int l = (rem >> 3) & 63; int e = rem & 7;
        int o = ct * 16 + (l & 15);
        int k = kk * 32 + (l >> 4) * 8 + e;
        const float* w = (task == 0 || o >= 64) ? kvws2mv : qws2mv;
        v = w[o * 128 + k];
    } else if (id < WS_TS_BASE) {
        int rem = id - WS_SW_BASE; int task = rem / 81920; rem -= task * 81920;
        int ct = rem / 2560; rem -= ct * 2560;
        int lr = rem / 160;  int k = rem - lr * 160;
        int o = s_chan(ct, lr);
        if (k < 32) {
            const float* w = (task == 0 || o >= 256) ? kvwmv2s : qwmv2s;
            v = w[o * 32 + k];
        } else {
            const float* w = (task == 0 || o >= 256) ? kvws2s : qws2s;
            v = w[o * 128 + (k - 32)];
        }
    } else {
        v = scalars[id - WS_TS_BASE];        // TS: straight bf16 copy
    }
    ws[id] = f2b(v);
}

// bf16 transposed copy of inputs: TIN[bn][x][i] = f2b(inputs[bn][i][x])
__global__ __launch_bounds__(256) void prep_tin(
    const float* __restrict__ inputs, short* __restrict__ ws)
{
    const int t  = blockIdx.x * 256 + threadIdx.x;   // 131072 threads
    const int x  = t & 15;
    const int bn = t >> 4;                           // [0, 8192)
    const float* src = inputs + (size_t)bn * 512 + x;
    short tmp[32];
    #pragma unroll
    for (int i = 0; i < 32; ++i) tmp[i] = f2b(src[i * 16]);  // lanes: 64B-coalesced per i
    short* dst = ws + WS_TIN_BASE + (size_t)bn * 512 + x * 32;
    #pragma unroll
    for (int j = 0; j < 4; ++j)
        *(bf16x8*)(dst + j * 8) = *(const bf16x8*)(tmp + j * 8);
}

// ======================= MV outputs =========================================
__global__ __launch_bounds__(256) void fused_mv(
    const int* __restrict__ q_idx, const int* __restrict__ kv_idx,
    const short* __restrict__ ws,  float* __restrict__ out)
{
    const int GR[16]   = {0,1,1,1,1,2,2,2,2,2,2,3,3,3,3,4};
    const int SRC[16]  = {-1,0,-1,-1,-1,2,3,4,-1,-1,-1,8,9,10,-1,14};
    const int EMAP[16] = {0,5,0,0,0,6,6,6,0,0,0,7,7,7,0,8};

    __shared__ short XA[16 * 520];   // [r][x:16][i:32], row stride 520 (bank-spread)
    __shared__ short XS[16 * 136];   // [r][k:128], stride 136

    const int tid  = threadIdx.x;
    const int bid  = blockIdx.x;
    const int tile = bid & 255;
    const int b    = (bid >> 8) & 1;
    const int task = bid >> 9;          // 0 = kv-task, 1 = q-task
    const int n0   = tile * 16;
    const int* ridx = task ? q_idx : kv_idx;

    // ---- staging: straight bf16 gather-copy (wide LDS writes) ----
    {
        const int r = tid >> 4, c = tid & 15;
        const int m = ridx[n0 + r];
        const short* srcA = ws + WS_TIN_BASE + (size_t)(b * NN + m) * 512 + c * 32;
        #pragma unroll
        for (int j = 0; j < 4; ++j)
            *(bf16x8*)(XA + r * 520 + c * 32 + j * 8) = *(const bf16x8*)(srcA + j * 8);
        const short* srcS = ws + WS_TS_BASE + (size_t)(b * NN + m) * 128 + c * 8;
        *(bf16x8*)(XS + r * 136 + c * 8) = *(const bf16x8*)(srcS);
    }
    __syncthreads();

    const int w  = tid >> 6;
    const int l  = tid & 63;
    const int lr = l & 15;
    const int lg = l >> 4;

    // ---- hoist all A fragments to registers (read LDS once) ----
    bf16x8 Ax[16];
    #pragma unroll
    for (int x = 0; x < 16; ++x)
        Ax[x] = *(const bf16x8*)(XA + lr * 520 + x * 32 + lg * 8);
    bf16x8 Sx[4];
    #pragma unroll
    for (int kk = 0; kk < 4; ++kk)
        Sx[kk] = *(const bf16x8*)(XS + lr * 136 + kk * 32 + lg * 8);

    #pragma unroll
    for (int cc = 0; cc < 2; ++cc) {
        const int ct = 2 * w + cc;
        bf16x8 Bg[9];
        #pragma unroll
        for (int y = 0; y < 9; ++y)
            Bg[y] = *(const bf16x8*)(ws + ((((size_t)task * 9 + y) * 8 + ct) * 64 + l) * 8);

        const int o    = ct * 16 + lr;
        const int hid  = (o >> 3) & 7, head = o & 7;
        size_t obase = task ? ((o >= 64) ? OFF_VMVQ : OFF_QMV)
                            : ((o >= 64) ? OFF_VMV  : OFF_KMV);
        const size_t rowco = obase + (((size_t)b * 8 + head) * NN) * 128 + (size_t)hid * 16;

        #pragma unroll
        for (int xc = 0; xc < 4; ++xc) {
            f32x4 acc[4];
            #pragma unroll
            for (int q = 0; q < 4; ++q) {
                const int x = xc * 4 + q;
                f32x4 a0 = {0.f, 0.f, 0.f, 0.f};
                a0 = __builtin_amdgcn_mfma_f32_16x16x32_bf16(Ax[x], Bg[GR[x]], a0, 0, 0, 0);
                if (SRC[x] >= 0)
                    a0 = __builtin_amdgcn_mfma_f32_16x16x32_bf16(Ax[SRC[x]], Bg[EMAP[x]], a0, 0, 0, 0);
                if (x == 0) {
                    #pragma unroll
                    for (int kk = 0; kk < 4; ++kk) {
                        bf16x8 bs2 = *(const bf16x8*)(ws + WS_BMV_END +
                                       ((((size_t)task * 4 + kk) * 8 + ct) * 64 + l) * 8);
                        a0 = __builtin_amdgcn_mfma_f32_16x16x32_bf16(Sx[kk], bs2, a0, 0, 0, 0);
                    }
                }
                acc[q] = a0;
            }
            #pragma unroll
            for (int j = 0; j < 4; ++j) {
                const int n = n0 + lg * 4 + j;
                float4 vv = make_float4(acc[0][j], acc[1][j], acc[2][j], acc[3][j]);
                *(float4*)(out + rowco + (size_t)n * 128 + xc * 4) = vv;
            }
        }
    }
}

// ============= S outputs: all-bf16 operands, float4 stores ==================
__global__ __launch_bounds__(256) void s_proj(
    const float* __restrict__ q_b_s,  const float* __restrict__ kv_b_s,
    const int* __restrict__ q_idx,    const int* __restrict__ kv_idx,
    const short* __restrict__ ws,     float* __restrict__ out)
{
    const int tid  = threadIdx.x;
    const int bid  = blockIdx.x;
    const int tile = bid & 255;
    const int b    = (bid >> 8) & 1;
    const int task = bid >> 9;
    const int n0   = tile * 16;
    const int* ridx = task ? q_idx : kv_idx;

    const int w  = tid >> 6;
    const int l  = tid & 63;
    const int lr = l & 15;
    const int lg = l >> 4;

    const int m = ridx[n0 + lr];   // this lane supplies A-row lr

    // A fragment, mv blade-0 = TIN x=0 slice
    bf16x8 a0 = *(const bf16x8*)(ws + WS_TIN_BASE + (size_t)(b * NN + m) * 512 + lg * 8);
    // A fragments, scalars (bf16 copy)
    bf16x8 as[4];
    #pragma unroll
    for (int c = 0; c < 4; ++c)
        as[c] = *(const bf16x8*)(ws + WS_TS_BASE + (size_t)(b * NN + m) * 128 + c * 32 + lg * 8);

    #pragma unroll
    for (int q8 = 0; q8 < 2; ++q8) {            // two quads of ct
        f32x4 acc4[4];
        #pragma unroll
        for (int jj = 0; jj < 4; ++jj) {
            const int ct = w * 8 + q8 * 4 + jj;
            const short* bp = ws + WS_SW_BASE +
                              (((size_t)task * 32 + ct) * 16 + lr) * 160 + lg * 8;
            f32x4 acc = {0.f, 0.f, 0.f, 0.f};
            acc = __builtin_amdgcn_mfma_f32_16x16x32_bf16(a0, *(const bf16x8*)bp, acc, 0, 0, 0);
            #pragma unroll
            for (int c = 0; c < 4; ++c)
                acc = __builtin_amdgcn_mfma_f32_16x16x32_bf16(
                          as[c], *(const bf16x8*)(bp + 32 + c * 32), acc, 0, 0, 0);
            acc4[jj] = acc;
        }
        const int hidbase = 16 * w + 8 * q8 + 4 * (lr >> 3);
        const int head = lr & 7;
        float bs[4];
        #pragma unroll
        for (int jj = 0; jj < 4; ++jj) {
            const int o = head + 8 * (hidbase + jj);
            bs[jj] = (task == 0) ? kv_b_s[o] : ((o < 256) ? q_b_s[o] : kv_b_s[o]);
        }
        size_t obase = task ? ((hidbase < 32) ? OFF_QS : OFF_VSQ)
                            : ((hidbase < 32) ? OFF_KS : OFF_VS);
        const size_t co = obase + (((size_t)b * 8 + head) * NN) * 32 + (hidbase & 31);
        #pragma unroll
        for (int j = 0; j < 4; ++j) {
            const int n = n0 + lg * 4 + j;
            float4 vv = make_float4(acc4[0][j] + bs[0], acc4[1][j] + bs[1],
                                    acc4[2][j] + bs[2], acc4[3][j] + bs[3]);
            *(float4*)(out + co + (size_t)n * 32) = vv;
        }
    }
}

extern "C" void kernel_launch(void* const* d_in, const int* in_sizes, int n_in,
                              void* d_out, int out_size, void* d_ws, size_t ws_size,
                              hipStream_t stream) {
    const float* inputs  = (const float*)d_in[0];
    const float* scalars = (const float*)d_in[1];
    const float* qwmv    = (const float*)d_in[2];
    const float* qws2mv  = (const float*)d_in[3];
    const float* qwmv2s  = (const float*)d_in[4];
    const float* qws2s   = (const float*)d_in[5];
    const float* qbs     = (const float*)d_in[6];
    const float* kvwmv   = (const float*)d_in[7];
    const float* kvws2mv = (const float*)d_in[8];
    const float* kvwmv2s = (const float*)d_in[9];
    const float* kvws2s  = (const float*)d_in[10];
    const float* kvbs    = (const float*)d_in[11];
    const int*   qidx    = (const int*)d_in[12];
    const int*   kvidx   = (const int*)d_in[13];
    short* ws   = (short*)d_ws;            // 11,026,432 B of scratch used
    float* outp = (float*)d_out;

    prep_pack<<<(WS_PACK_END + 255) / 256, 256, 0, stream>>>(
        scalars, qwmv, qws2mv, qwmv2s, qws2s, kvwmv, kvws2mv, kvwmv2s, kvws2s, ws);

    prep_tin<<<512, 256, 0, stream>>>(inputs, ws);

    fused_mv<<<1024, 256, 0, stream>>>(qidx, kvidx, ws, outp);

    s_proj<<<1024, 256, 0, stream>>>(qbs, kvbs, qidx, kvidx, ws, outp);
}

// Round 5
// 64.254 us; speedup vs baseline: 1.9393x; 1.3761x over previous
//
#include <hip/hip_runtime.h>
#include <hip/hip_bf16.h>
#include <stdint.h>

typedef short bf16x8 __attribute__((ext_vector_type(8)));
typedef float f32x4 __attribute__((ext_vector_type(4)));

#define NN 4096

static __device__ __forceinline__ short f2b(float f) {
    union { float f; uint32_t u; } a; a.f = f;
    uint32_t r = a.u + 0x7FFFu + ((a.u >> 16) & 1u);
    return (short)(r >> 16);
}

// ---- output region offsets (in floats) ----
#define OFF_QMV   0UL
#define OFF_KMV   8388608UL
#define OFF_VMV   16777216UL
#define OFF_VMVQ  25165824UL
#define OFF_QS    33554432UL
#define OFF_KS    35651584UL
#define OFF_VS    37748736UL
#define OFF_VSQ   39845888UL

// ---- ws layout (bf16 elements) ----
// Bmv:   [task][y:9][ct:8][lane:64][e:8]    = 73728
// Bs2mv: [task][kk:4][ct:8][lane:64][e:8]   = 32768
// SW:    [task][ct:32][lr:16][k:160]        = 163840
// TS:    [b:2][n:4096][k:128]   bf16 scalars copy      = 1048576
// TIN:   [b:2][n:4096][x:16][i:32] bf16 transposed mv  = 4194304
#define WS_BMV_END   73728
#define WS_SW_BASE   106496
#define WS_TS_BASE   270336
#define WS_PACK_END  1318912
#define WS_TIN_BASE  1318912
#define WS_TOTAL     5513216   // shorts -> 11,026,432 bytes of scratch

// MV-GEMM column-channel map: (ct, lane) -> output channel O in [0,128)
//   region = ct>>2 (0: k/q, 1: v/v_q), hid = l&7, head = (ct&3)*2 + ((l>>3)&1)
static __device__ __forceinline__ int mv_chan(int ct, int l) {
    return (ct >> 2) * 64 + (l & 7) * 8 + (ct & 3) * 2 + ((l >> 3) & 1);
}

// col-channel mapping for the S GEMM: o(ct,lr) — bijective, bit-disjoint
static __device__ __forceinline__ int s_chan(int ct, int lr) {
    int hid = (ct & 3) + 4 * (lr >> 3) + 8 * (ct >> 2);
    return (lr & 7) + 8 * hid;
}

// ============ prep: weight packs + bf16 copies/transposes ===================
__global__ __launch_bounds__(256) void prep_all(
    const float* __restrict__ inputs, const float* __restrict__ scalars,
    const float* __restrict__ qwmv,   const float* __restrict__ qws2mv,
    const float* __restrict__ qwmv2s, const float* __restrict__ qws2s,
    const float* __restrict__ kvwmv,  const float* __restrict__ kvws2mv,
    const float* __restrict__ kvwmv2s,const float* __restrict__ kvws2s,
    short* __restrict__ ws)
{
    if (blockIdx.x < 512) {
        // TIN: bf16 transposed inputs, TIN[bn][x][i] = f2b(inputs[bn][i][x])
        const int t  = blockIdx.x * 256 + threadIdx.x;
        const int x  = t & 15;
        const int bn = t >> 4;
        const float* src = inputs + (size_t)bn * 512 + x;
        short tmp[32];
        #pragma unroll
        for (int i = 0; i < 32; ++i) tmp[i] = f2b(src[i * 16]);
        short* dst = ws + WS_TIN_BASE + (size_t)bn * 512 + x * 32;
        #pragma unroll
        for (int j = 0; j < 4; ++j)
            *(bf16x8*)(dst + j * 8) = *(const bf16x8*)(tmp + j * 8);
        return;
    }
    int id = (blockIdx.x - 512) * 256 + threadIdx.x;
    if (id >= WS_PACK_END) return;
    float v;
    if (id < WS_BMV_END) {
        int rem = id; int task = rem / 36864; rem -= task * 36864;
        int y = rem / 4096; rem -= y * 4096;
        int ct = rem >> 9; int l = (rem >> 3) & 63; int e = rem & 7;
        int o = mv_chan(ct, l);
        int i = (l >> 4) * 8 + e;
        const float* w = (task == 0 || o >= 64) ? kvwmv : qwmv;
        v = w[(o * 32 + i) * 9 + y];
    } else if (id < WS_SW_BASE) {
        int rem = id - WS_BMV_END; int task = rem / 16384; rem -= task * 16384;
        int kk = rem / 4096; rem -= kk * 4096;
        int ct = rem >> 9; int l = (rem >> 3) & 63; int e = rem & 7;
        int o = mv_chan(ct, l);
        int k = kk * 32 + (l >> 4) * 8 + e;
        const float* w = (task == 0 || o >= 64) ? kvws2mv : qws2mv;
        v = w[o * 128 + k];
    } else if (id < WS_TS_BASE) {
        int rem = id - WS_SW_BASE; int task = rem / 81920; rem -= task * 81920;
        int ct = rem / 2560; rem -= ct * 2560;
        int lr = rem / 160;  int k = rem - lr * 160;
        int o = s_chan(ct, lr);
        if (k < 32) {
            const float* w = (task == 0 || o >= 256) ? kvwmv2s : qwmv2s;
            v = w[o * 32 + k];
        } else {
            const float* w = (task == 0 || o >= 256) ? kvws2s : qws2s;
            v = w[o * 128 + (k - 32)];
        }
    } else {
        v = scalars[id - WS_TS_BASE];        // TS: straight bf16 copy
    }
    ws[id] = f2b(v);
}

// ======================= MV outputs: LDS-transposed coalesced stores ========
__global__ __launch_bounds__(256) void fused_mv(
    const int* __restrict__ q_idx, const int* __restrict__ kv_idx,
    const short* __restrict__ ws,  float* __restrict__ out)
{
    const int GR[16]   = {0,1,1,1,1,2,2,2,2,2,2,3,3,3,3,4};
    const int SRC[16]  = {-1,0,-1,-1,-1,2,3,4,-1,-1,-1,8,9,10,-1,14};
    const int EMAP[16] = {0,5,0,0,0,6,6,6,0,0,0,7,7,7,0,8};

    __shared__ __align__(16) char SMEM[65536];
    short* XA = (short*)SMEM;            // [r:16][x:16][i:32], row stride 520
    short* XS = XA + 16 * 520;           // [r:16][k:128], stride 136

    const int tid  = threadIdx.x;
    const int bid  = blockIdx.x;
    const int tile = bid & 255;
    const int b    = (bid >> 8) & 1;
    const int task = bid >> 9;          // 0 = kv-task, 1 = q-task
    const int n0   = tile * 16;
    const int* ridx = task ? q_idx : kv_idx;

    // ---- staging: straight bf16 gather-copy (wide LDS writes) ----
    {
        const int r = tid >> 4, c = tid & 15;
        const int m = ridx[n0 + r];
        const short* srcA = ws + WS_TIN_BASE + (size_t)(b * NN + m) * 512 + c * 32;
        #pragma unroll
        for (int j = 0; j < 4; ++j)
            *(bf16x8*)(XA + r * 520 + c * 32 + j * 8) = *(const bf16x8*)(srcA + j * 8);
        const short* srcS = ws + WS_TS_BASE + (size_t)(b * NN + m) * 128 + c * 8;
        *(bf16x8*)(XS + r * 136 + c * 8) = *(const bf16x8*)(srcS);
    }
    __syncthreads();

    const int w  = tid >> 6;
    const int l  = tid & 63;
    const int lr = l & 15;
    const int lg = l >> 4;

    // ---- hoist all A fragments to registers (read LDS once) ----
    bf16x8 Ax[16];
    #pragma unroll
    for (int x = 0; x < 16; ++x)
        Ax[x] = *(const bf16x8*)(XA + lr * 520 + x * 32 + lg * 8);
    bf16x8 Sx[4];
    #pragma unroll
    for (int kk = 0; kk < 4; ++kk)
        Sx[kk] = *(const bf16x8*)(XS + lr * 136 + kk * 32 + lg * 8);
    __syncthreads();   // XA/XS dead; SMEM becomes per-wave OUT buffers

    float* OUTw = (float*)SMEM + w * 4096;   // [row:32][128 floats], 16 KB/wave

    #pragma unroll
    for (int cc = 0; cc < 2; ++cc) {
        const int ct = 2 * w + cc;
        bf16x8 Bg[9];
        #pragma unroll
        for (int y = 0; y < 9; ++y)
            Bg[y] = *(const bf16x8*)(ws + ((((size_t)task * 9 + y) * 8 + ct) * 64 + l) * 8);

        #pragma unroll
        for (int xc = 0; xc < 4; ++xc) {
            f32x4 acc[4];
            #pragma unroll
            for (int q = 0; q < 4; ++q) {
                const int x = xc * 4 + q;
                f32x4 a0 = {0.f, 0.f, 0.f, 0.f};
                a0 = __builtin_amdgcn_mfma_f32_16x16x32_bf16(Ax[x], Bg[GR[x]], a0, 0, 0, 0);
                if (SRC[x] >= 0)
                    a0 = __builtin_amdgcn_mfma_f32_16x16x32_bf16(Ax[SRC[x]], Bg[EMAP[x]], a0, 0, 0, 0);
                if (x == 0) {
                    #pragma unroll
                    for (int kk = 0; kk < 4; ++kk) {
                        bf16x8 bs2 = *(const bf16x8*)(ws + WS_BMV_END +
                                       ((((size_t)task * 4 + kk) * 8 + ct) * 64 + l) * 8);
                        a0 = __builtin_amdgcn_mfma_f32_16x16x32_bf16(Sx[kk], bs2, a0, 0, 0, 0);
                    }
                }
                acc[q] = a0;
            }
            // dump x-quad to wave-private OUT: row=(h2,n), col-quad=(hid,xc), swizzled
            #pragma unroll
            for (int j = 0; j < 4; ++j) {
                const int roww = (lr >> 3) * 16 + lg * 4 + j;
                const int cqw  = ((lr & 7) * 4 + xc) ^ ((roww >> 2) & 7);
                *(f32x4*)(OUTw + roww * 128 + cqw * 4) =
                    (f32x4){acc[0][j], acc[1][j], acc[2][j], acc[3][j]};
            }
        }

        // readback + coalesced store: each instr = 1 KB contiguous (2 rows)
        const int region = ct >> 2;
        const size_t obase = task ? (region ? OFF_VMVQ : OFF_QMV)
                                  : (region ? OFF_VMV  : OFF_KMV);
        #pragma unroll
        for (int t = 0; t < 16; ++t) {
            const int row  = 2 * t + (l >> 5);
            const int h2   = row >> 4, nl = row & 15;
            const int head = (ct & 3) * 2 + h2;
            const int cq   = (l & 31) ^ ((row >> 2) & 7);
            f32x4 v = *(const f32x4*)(OUTw + row * 128 + cq * 4);
            *(f32x4*)(out + obase + (((size_t)(b * 8 + head)) * NN + n0 + nl) * 128
                      + (l & 31) * 4) = v;
        }
    }
}

// ============= S outputs: all-bf16 operands, float4 stores ==================
__global__ __launch_bounds__(256) void s_proj(
    const float* __restrict__ q_b_s,  const float* __restrict__ kv_b_s,
    const int* __restrict__ q_idx,    const int* __restrict__ kv_idx,
    const short* __restrict__ ws,     float* __restrict__ out)
{
    const int tid  = threadIdx.x;
    const int bid  = blockIdx.x;
    const int tile = bid & 255;
    const int b    = (bid >> 8) & 1;
    const int task = bid >> 9;
    const int n0   = tile * 16;
    const int* ridx = task ? q_idx : kv_idx;

    const int w  = tid >> 6;
    const int l  = tid & 63;
    const int lr = l & 15;
    const int lg = l >> 4;

    const int m = ridx[n0 + lr];   // this lane supplies A-row lr

    // A fragment, mv blade-0 = TIN x=0 slice
    bf16x8 a0 = *(const bf16x8*)(ws + WS_TIN_BASE + (size_t)(b * NN + m) * 512 + lg * 8);
    // A fragments, scalars (bf16 copy)
    bf16x8 as[4];
    #pragma unroll
    for (int c = 0; c < 4; ++c)
        as[c] = *(const bf16x8*)(ws + WS_TS_BASE + (size_t)(b * NN + m) * 128 + c * 32 + lg * 8);

    #pragma unroll
    for (int q8 = 0; q8 < 2; ++q8) {            // two quads of ct
        f32x4 acc4[4];
        #pragma unroll
        for (int jj = 0; jj < 4; ++jj) {
            const int ct = w * 8 + q8 * 4 + jj;
            const short* bp = ws + WS_SW_BASE +
                              (((size_t)task * 32 + ct) * 16 + lr) * 160 + lg * 8;
            f32x4 acc = {0.f, 0.f, 0.f, 0.f};
            acc = __builtin_amdgcn_mfma_f32_16x16x32_bf16(a0, *(const bf16x8*)bp, acc, 0, 0, 0);
            #pragma unroll
            for (int c = 0; c < 4; ++c)
                acc = __builtin_amdgcn_mfma_f32_16x16x32_bf16(
                          as[c], *(const bf16x8*)(bp + 32 + c * 32), acc, 0, 0, 0);
            acc4[jj] = acc;
        }
        const int hidbase = 16 * w + 8 * q8 + 4 * (lr >> 3);
        const int head = lr & 7;
        float bs[4];
        #pragma unroll
        for (int jj = 0; jj < 4; ++jj) {
            const int o = head + 8 * (hidbase + jj);
            bs[jj] = (task == 0) ? kv_b_s[o] : ((o < 256) ? q_b_s[o] : kv_b_s[o]);
        }
        size_t obase = task ? ((hidbase < 32) ? OFF_QS : OFF_VSQ)
                            : ((hidbase < 32) ? OFF_KS : OFF_VS);
        const size_t co = obase + (((size_t)b * 8 + head) * NN) * 32 + (hidbase & 31);
        #pragma unroll
        for (int j = 0; j < 4; ++j) {
            const int n = n0 + lg * 4 + j;
            float4 vv = make_float4(acc4[0][j] + bs[0], acc4[1][j] + bs[1],
                                    acc4[2][j] + bs[2], acc4[3][j] + bs[3]);
            *(float4*)(out + co + (size_t)n * 32) = vv;
        }
    }
}

extern "C" void kernel_launch(void* const* d_in, const int* in_sizes, int n_in,
                              void* d_out, int out_size, void* d_ws, size_t ws_size,
                              hipStream_t stream) {
    const float* inputs  = (const float*)d_in[0];
    const float* scalars = (const float*)d_in[1];
    const float* qwmv    = (const float*)d_in[2];
    const float* qws2mv  = (const float*)d_in[3];
    const float* qwmv2s  = (const float*)d_in[4];
    const float* qws2s   = (const float*)d_in[5];
    const float* qbs     = (const float*)d_in[6];
    const float* kvwmv   = (const float*)d_in[7];
    const float* kvws2mv = (const float*)d_in[8];
    const float* kvwmv2s = (const float*)d_in[9];
    const float* kvws2s  = (const float*)d_in[10];
    const float* kvbs    = (const float*)d_in[11];
    const int*   qidx    = (const int*)d_in[12];
    const int*   kvidx   = (const int*)d_in[13];
    short* ws   = (short*)d_ws;            // 11,026,432 B of scratch used
    float* outp = (float*)d_out;

    const int packBlocks = 512 + (WS_PACK_END + 255) / 256;
    prep_all<<<packBlocks, 256, 0, stream>>>(
        inputs, scalars, qwmv, qws2mv, qwmv2s, qws2s,
        kvwmv, kvws2mv, kvwmv2s, kvws2s, ws);

    fused_mv<<<1024, 256, 0, stream>>>(qidx, kvidx, ws, outp);

    s_proj<<<1024, 256, 0, stream>>>(qbs, kvbs, qidx, kvidx, ws, outp);
}